// Round 1
// baseline (4050.169 us; speedup 1.0000x reference)
//
#include <hip/hip_runtime.h>

#define HH 256
#define WW 256
#define HW (HH * WW)

// ---------------------------------------------------------------------------
// Direct 3x3 conv, padding 1, NCHW fp32. Each block: 16x16 spatial tile, each
// thread computes all COUT channels for its pixel. Input staged in LDS in
// CI_CHUNK channel slices; weights are block-uniform -> scalar loads.
// Optional fused ReLU / fused residual add (same-element, in-place safe).
// ---------------------------------------------------------------------------
template <int CIN, int COUT, bool RELU, bool ADDRES>
__global__ __launch_bounds__(256) void conv3k(const float* __restrict__ in,
                                              const float* __restrict__ wgt,
                                              const float* __restrict__ bias,
                                              const float* __restrict__ res,
                                              float* __restrict__ out) {
    constexpr int CI_CHUNK = 16;
    __shared__ float tile[CI_CHUNK][18][18];

    const int tid = threadIdx.x;
    const int lx = tid & 15, ly = tid >> 4;
    const int bx = blockIdx.x << 4, by = blockIdx.y << 4;
    const int b = blockIdx.z;
    const int px = bx + lx, py = by + ly;

    float acc[COUT];
#pragma unroll
    for (int o = 0; o < COUT; ++o) acc[o] = 0.f;

    const float* inb = in + (size_t)b * CIN * HW;

    for (int c0 = 0; c0 < CIN; c0 += CI_CHUNK) {
        // cooperative load of 18x18 halo tile for CI_CHUNK channels
        for (int idx = tid; idx < CI_CHUNK * 324; idx += 256) {
            int ci = idx / 324;
            int r = idx - ci * 324;
            int iy = r / 18;
            int ix = r - iy * 18;
            int gy = by - 1 + iy;
            int gx = bx - 1 + ix;
            float v = 0.f;
            if ((unsigned)gy < HH && (unsigned)gx < WW)
                v = inb[(size_t)(c0 + ci) * HW + gy * WW + gx];
            tile[ci][iy][ix] = v;
        }
        __syncthreads();

#pragma unroll 1
        for (int ci = 0; ci < CI_CHUNK; ++ci) {
            float v[9];
#pragma unroll
            for (int t = 0; t < 9; ++t)
                v[t] = tile[ci][ly + t / 3][lx + t % 3];
            const int cg = c0 + ci;
#pragma unroll
            for (int o = 0; o < COUT; ++o) {
                const float* wo = wgt + ((size_t)o * CIN + cg) * 9;
                float a = acc[o];
                a = fmaf(v[0], wo[0], a);
                a = fmaf(v[1], wo[1], a);
                a = fmaf(v[2], wo[2], a);
                a = fmaf(v[3], wo[3], a);
                a = fmaf(v[4], wo[4], a);
                a = fmaf(v[5], wo[5], a);
                a = fmaf(v[6], wo[6], a);
                a = fmaf(v[7], wo[7], a);
                a = fmaf(v[8], wo[8], a);
                acc[o] = a;
            }
        }
        __syncthreads();
    }

    const size_t obase = (size_t)b * COUT * HW + (size_t)py * WW + px;
#pragma unroll
    for (int o = 0; o < COUT; ++o) {
        float vv = acc[o] + bias[o];
        if (RELU) vv = fmaxf(vv, 0.f);
        if (ADDRES) vv += res[obase + (size_t)o * HW];
        out[obase + (size_t)o * HW] = vv;
    }
}

// ---------------------------------------------------------------------------
// Deformable 3x3 conv, 32->32 channels. The grid offsets cancel with the
// modulation's grid subtraction, so tap k samples at
//   (y + off0[b, (3+k)*2+1]*0.08, x + off0[b, (3+k)*2]*0.08)
// with zero-padded bilinear gather (per-corner validity), weight w[o,c,k%3,k/3].
// One thread per pixel, 32 output-channel accumulators in registers.
// ---------------------------------------------------------------------------
template <bool RELU, bool ADDRES>
__global__ __launch_bounds__(256) void dconv32(const float* __restrict__ in,
                                               const float* __restrict__ off0,
                                               const float* __restrict__ wgt,
                                               const float* __restrict__ bias,
                                               const float* __restrict__ res,
                                               float* __restrict__ out) {
    const int gtid = blockIdx.x * 256 + threadIdx.x;
    const int x = gtid & 255;
    const int y = (gtid >> 8) & 255;
    const int b = gtid >> 16;
    const int pix = y * WW + x;

    float acc[32];
#pragma unroll
    for (int o = 0; o < 32; ++o) acc[o] = 0.f;

    const float* inb = in + (size_t)b * 32 * HW;
    const float* offb = off0 + (size_t)b * 24 * HW + pix;

#pragma unroll 1
    for (int k = 0; k < 9; ++k) {
        float dx = offb[(size_t)(6 + 2 * k) * HW] * 0.08f;
        float dy = offb[(size_t)(7 + 2 * k) * HW] * 0.08f;
        float pxf = (float)x + dx;
        float pyf = (float)y + dy;
        float x0f = floorf(pxf), y0f = floorf(pyf);
        float wx = pxf - x0f, wy = pyf - y0f;
        int x0 = (int)x0f, y0 = (int)y0f;
        int x1 = x0 + 1, y1 = y0 + 1;
        float vx0 = ((unsigned)x0 < WW) ? 1.f : 0.f;
        float vx1 = ((unsigned)x1 < WW) ? 1.f : 0.f;
        float vy0 = ((unsigned)y0 < HH) ? 1.f : 0.f;
        float vy1 = ((unsigned)y1 < HH) ? 1.f : 0.f;
        int xc0 = min(max(x0, 0), WW - 1), xc1 = min(max(x1, 0), WW - 1);
        int yc0 = min(max(y0, 0), HH - 1), yc1 = min(max(y1, 0), HH - 1);
        float w00 = (1.f - wy) * (1.f - wx) * vy0 * vx0;
        float w01 = (1.f - wy) * wx * vy0 * vx1;
        float w10 = wy * (1.f - wx) * vy1 * vx0;
        float w11 = wy * wx * vy1 * vx1;
        int o00 = yc0 * WW + xc0, o01 = yc0 * WW + xc1;
        int o10 = yc1 * WW + xc0, o11 = yc1 * WW + xc1;

        const float* wk = wgt + (k % 3) * 3 + (k / 3);
#pragma unroll 1
        for (int c = 0; c < 32; ++c) {
            const float* p = inb + (size_t)c * HW;
            float s = w00 * p[o00] + w01 * p[o01] + w10 * p[o10] + w11 * p[o11];
#pragma unroll
            for (int o = 0; o < 32; ++o)
                acc[o] = fmaf(s, wk[(o * 32 + c) * 9], acc[o]);
        }
    }

    const size_t obase = (size_t)b * 32 * HW + pix;
#pragma unroll
    for (int o = 0; o < 32; ++o) {
        float vv = acc[o] + bias[o];
        if (RELU) vv = fmaxf(vv, 0.f);
        if (ADDRES) vv += res[obase + (size_t)o * HW];
        out[obase + (size_t)o * HW] = vv;
    }
}

extern "C" void kernel_launch(void* const* d_in, const int* in_sizes, int n_in,
                              void* d_out, int out_size, void* d_ws, size_t ws_size,
                              hipStream_t stream) {
    const float* x    = (const float*)d_in[0];
    const float* off0 = (const float*)d_in[1];
    const float* w12  = (const float*)d_in[2];
    const float* b12  = (const float*)d_in[3];
    const float* w13a = (const float*)d_in[4];
    const float* b13a = (const float*)d_in[5];
    const float* w13b = (const float*)d_in[6];
    const float* b13b = (const float*)d_in[7];
    const float* w14a = (const float*)d_in[8];
    const float* b14a = (const float*)d_in[9];
    const float* w14b = (const float*)d_in[10];
    const float* b14b = (const float*)d_in[11];
    const float* w15  = (const float*)d_in[12];
    const float* b15  = (const float*)d_in[13];
    const float* w50  = (const float*)d_in[14];
    const float* b50  = (const float*)d_in[15];
    const float* w51  = (const float*)d_in[16];
    const float* b51  = (const float*)d_in[17];
    const float* w60  = (const float*)d_in[18];
    const float* b60  = (const float*)d_in[19];
    const float* w61  = (const float*)d_in[20];
    const float* b61  = (const float*)d_in[21];
    const float* w24  = (const float*)d_in[22];
    const float* b24  = (const float*)d_in[23];

    // workspace layout: A (64ch, 33.5MB) | B (64ch, 33.5MB); 32-ch buffers
    // D,E alias B once B's 64-ch content is dead.
    float* A  = (float*)d_ws;
    float* Bb = A + (size_t)2 * 64 * HW;
    float* D  = Bb;
    float* E  = Bb + (size_t)2 * 32 * HW;
    float* out = (float*)d_out;

    dim3 grid(WW / 16, HH / 16, 2);

    conv3k<64, 64, false, false><<<grid, 256, 0, stream>>>(x, w12, b12, nullptr, A);
    conv3k<64, 64, true,  false><<<grid, 256, 0, stream>>>(A, w13a, b13a, nullptr, Bb);
    conv3k<64, 64, false, true ><<<grid, 256, 0, stream>>>(Bb, w13b, b13b, A, A);
    conv3k<64, 64, true,  false><<<grid, 256, 0, stream>>>(A, w14a, b14a, nullptr, Bb);
    conv3k<64, 64, false, true ><<<grid, 256, 0, stream>>>(Bb, w14b, b14b, A, A);
    conv3k<64, 32, false, false><<<grid, 256, 0, stream>>>(A, w15, b15, nullptr, D);

    dconv32<true,  false><<<512, 256, 0, stream>>>(D, off0, w50, b50, nullptr, E);
    dconv32<false, true ><<<512, 256, 0, stream>>>(E, off0, w51, b51, D, D);
    dconv32<true,  false><<<512, 256, 0, stream>>>(D, off0, w60, b60, nullptr, E);
    dconv32<false, true ><<<512, 256, 0, stream>>>(E, off0, w61, b61, D, D);

    conv3k<32, 3, false, false><<<grid, 256, 0, stream>>>(D, w24, b24, nullptr, out);
}

// Round 2
// 882.363 us; speedup vs baseline: 4.5901x; 4.5901x over previous
//
#include <hip/hip_runtime.h>

#define HH 256
#define WW 256
#define HW (HH * WW)

typedef float f32x4 __attribute__((ext_vector_type(4)));
typedef short bf16x8 __attribute__((ext_vector_type(8)));

__device__ __forceinline__ unsigned short f2bf(float f) {
    union { float f; unsigned u; } v; v.f = f;
    unsigned r = v.u + 0x7fff + ((v.u >> 16) & 1);   // RNE
    return (unsigned short)(r >> 16);
}

// ---------------------------------------------------------------------------
// Weight prepack: fp32 OIHW -> bf16 [tap][kc][cout][k32] where tap t = ky*3+kx,
// k32 = k-within-32 (kg*8+j), cin = kc*32 + k32. A-frag for lane l is then a
// single contiguous 16B load at ((t*KC+kc)*COUT + cout)*32 + (l>>4)*8.
// ---------------------------------------------------------------------------
__global__ void prepack(const float* __restrict__ w, unsigned short* __restrict__ dst,
                        int COUT, int CIN) {
    int n = COUT * CIN * 9;
    int i = blockIdx.x * 256 + threadIdx.x;
    if (i >= n) return;
    int q = i & 31;
    int rest = i >> 5;
    int o = rest % COUT;
    int rest2 = rest / COUT;
    int KC = CIN >> 5;
    int kc = rest2 % KC;
    int t = rest2 / KC;
    int cin = kc * 32 + q;
    float v = w[((o * CIN + cin) * 3 + t / 3) * 3 + (t % 3)];
    dst[i] = f2bf(v);
}

// ---------------------------------------------------------------------------
// 3x3 conv via bf16 MFMA implicit GEMM. Block tile: 32w x 4h pixels (halo
// 34x6 staged bf16 pixel-major in LDS), COUT channels. Wave = 32 cout x 64
// pix. WM = COUT/32 M-wave-groups x 2 N-wave-groups. A-frags from prepacked
// global (L1-hot), B-frags ds_read_b128 from LDS; tap shift = constant LDS
// pixel offset. fp32 accum; fused bias/ReLU/residual epilogue.
// ---------------------------------------------------------------------------
template <int CIN, int COUT, bool RELU, bool ADDRES>
__global__ __launch_bounds__((COUT / 32) * 128) void convmfma(
    const float* __restrict__ in, const unsigned short* __restrict__ wp,
    const float* __restrict__ bias, const float* __restrict__ res,
    float* __restrict__ out) {
    constexpr int KC = CIN / 32;
    constexpr int WM = COUT / 32;
    constexpr int NT = WM * 128;
    constexpr int CSTR = (CIN == 64) ? 72 : 40;  // row stride: 16B-aligned, 4*odd banks
    __shared__ unsigned short xt[204 * CSTR];

    const int tid = threadIdx.x;
    const int b = blockIdx.z;
    const int bx0 = blockIdx.x * 32;
    const int by0 = blockIdx.y * 4;

    // ---- stage 34x6 halo tile, CIN channels, bf16 [pix][cin] ----
    const float* inb = in + (size_t)b * CIN * HW;
    for (int hp = tid; hp < 204; hp += NT) {
        int hy = hp / 34, hx = hp - hy * 34;
        int gy = by0 + hy - 1, gx = bx0 + hx - 1;
        bool ok = ((unsigned)gy < HH) && ((unsigned)gx < WW);
        const float* src = inb + ((size_t)gy * WW + gx);
        unsigned* dstp = (unsigned*)&xt[hp * CSTR];
#pragma unroll 4
        for (int c = 0; c < CIN; c += 2) {
            float v0 = ok ? src[(size_t)c * HW] : 0.f;
            float v1 = ok ? src[(size_t)(c + 1) * HW] : 0.f;
            dstp[c >> 1] = (unsigned)f2bf(v0) | ((unsigned)f2bf(v1) << 16);
        }
    }
    __syncthreads();

    // ---- wave / lane decomposition ----
    const int lane = tid & 63;
    const int wv = tid >> 6;
    const int wm = (WM == 2) ? (wv & 1) : 0;
    const int wn = (WM == 2) ? (wv >> 1) : wv;
    const int l15 = lane & 15;
    const int kg = lane >> 4;

    f32x4 acc[2][4];
#pragma unroll
    for (int m = 0; m < 2; ++m)
#pragma unroll
        for (int n = 0; n < 4; ++n) acc[m][n] = {0.f, 0.f, 0.f, 0.f};

    int hbase[4];
#pragma unroll
    for (int n = 0; n < 4; ++n) {
        int p = wn * 64 + n * 16 + l15;
        hbase[n] = (p >> 5) * 34 + (p & 31);
    }

    // per-lane base into packed weights (elements)
    const unsigned short* wlane = wp + ((size_t)(wm * 32 + l15) * 4 + kg) * 8;

#pragma unroll
    for (int t = 0; t < 9; ++t) {
        bf16x8 afr[2][KC];
#pragma unroll
        for (int kc = 0; kc < KC; ++kc)
#pragma unroll
            for (int m = 0; m < 2; ++m)
                afr[m][kc] = *(const bf16x8*)(wlane + ((size_t)(t * KC + kc) * COUT + m * 16) * 32);

        const int hoff = (t / 3) * 34 + (t % 3);
#pragma unroll
        for (int kc = 0; kc < KC; ++kc) {
            bf16x8 bfr[4];
#pragma unroll
            for (int n = 0; n < 4; ++n) {
                const unsigned short* pB = &xt[(hbase[n] + hoff) * CSTR + kc * 32 + kg * 8];
                bfr[n] = *(const bf16x8*)pB;
            }
#pragma unroll
            for (int m = 0; m < 2; ++m)
#pragma unroll
                for (int n = 0; n < 4; ++n)
                    acc[m][n] = __builtin_amdgcn_mfma_f32_16x16x32_bf16(afr[m][kc], bfr[n], acc[m][n], 0, 0, 0);
        }
    }

    // ---- epilogue: D col=lane&15 (pixel), row=(lane>>4)*4+r (cout) ----
    const size_t obase = (size_t)b * COUT * HW;
#pragma unroll
    for (int m = 0; m < 2; ++m) {
#pragma unroll
        for (int n = 0; n < 4; ++n) {
            int p = wn * 64 + n * 16 + l15;
            int gy = by0 + (p >> 5), gx = bx0 + (p & 31);
#pragma unroll
            for (int r = 0; r < 4; ++r) {
                int cout = wm * 32 + m * 16 + kg * 4 + r;
                float v = acc[m][n][r] + bias[cout];
                if (RELU) v = fmaxf(v, 0.f);
                size_t oi = obase + (size_t)cout * HW + (size_t)gy * WW + gx;
                if (ADDRES) v += res[oi];
                out[oi] = v;
            }
        }
    }
}

// ---------------------------------------------------------------------------
// Direct 3x3 conv (kept for the tiny 32->3 final layer).
// ---------------------------------------------------------------------------
template <int CIN, int COUT, bool RELU, bool ADDRES>
__global__ __launch_bounds__(256) void conv3k(const float* __restrict__ in,
                                              const float* __restrict__ wgt,
                                              const float* __restrict__ bias,
                                              const float* __restrict__ res,
                                              float* __restrict__ out) {
    constexpr int CI_CHUNK = 16;
    __shared__ float tile[CI_CHUNK][18][18];

    const int tid = threadIdx.x;
    const int lx = tid & 15, ly = tid >> 4;
    const int bx = blockIdx.x << 4, by = blockIdx.y << 4;
    const int b = blockIdx.z;
    const int px = bx + lx, py = by + ly;

    float acc[COUT];
#pragma unroll
    for (int o = 0; o < COUT; ++o) acc[o] = 0.f;

    const float* inb = in + (size_t)b * CIN * HW;

    for (int c0 = 0; c0 < CIN; c0 += CI_CHUNK) {
        for (int idx = tid; idx < CI_CHUNK * 324; idx += 256) {
            int ci = idx / 324;
            int r = idx - ci * 324;
            int iy = r / 18;
            int ix = r - iy * 18;
            int gy = by - 1 + iy;
            int gx = bx - 1 + ix;
            float v = 0.f;
            if ((unsigned)gy < HH && (unsigned)gx < WW)
                v = inb[(size_t)(c0 + ci) * HW + gy * WW + gx];
            tile[ci][iy][ix] = v;
        }
        __syncthreads();

#pragma unroll 1
        for (int ci = 0; ci < CI_CHUNK; ++ci) {
            float v[9];
#pragma unroll
            for (int t = 0; t < 9; ++t)
                v[t] = tile[ci][ly + t / 3][lx + t % 3];
            const int cg = c0 + ci;
#pragma unroll
            for (int o = 0; o < COUT; ++o) {
                const float* wo = wgt + ((size_t)o * CIN + cg) * 9;
                float a = acc[o];
#pragma unroll
                for (int t = 0; t < 9; ++t) a = fmaf(v[t], wo[t], a);
                acc[o] = a;
            }
        }
        __syncthreads();
    }

    const size_t obase = (size_t)b * COUT * HW + (size_t)py * WW + px;
#pragma unroll
    for (int o = 0; o < COUT; ++o) {
        float vv = acc[o] + bias[o];
        if (RELU) vv = fmaxf(vv, 0.f);
        if (ADDRES) vv += res[obase + (size_t)o * HW];
        out[obase + (size_t)o * HW] = vv;
    }
}

// ---------------------------------------------------------------------------
// Deformable 3x3 conv 32->32 (fp32 direct; grid offsets cancel so tap k
// samples at (y + off0[b,(3+k)*2+1]*.08, x + off0[b,(3+k)*2]*.08), weight
// w[o][c][k%3][k/3]).
// ---------------------------------------------------------------------------
template <bool RELU, bool ADDRES>
__global__ __launch_bounds__(256) void dconv32(const float* __restrict__ in,
                                               const float* __restrict__ off0,
                                               const float* __restrict__ wgt,
                                               const float* __restrict__ bias,
                                               const float* __restrict__ res,
                                               float* __restrict__ out) {
    const int gtid = blockIdx.x * 256 + threadIdx.x;
    const int x = gtid & 255;
    const int y = (gtid >> 8) & 255;
    const int b = gtid >> 16;
    const int pix = y * WW + x;

    float acc[32];
#pragma unroll
    for (int o = 0; o < 32; ++o) acc[o] = 0.f;

    const float* inb = in + (size_t)b * 32 * HW;
    const float* offb = off0 + (size_t)b * 24 * HW + pix;

#pragma unroll 1
    for (int k = 0; k < 9; ++k) {
        float dx = offb[(size_t)(6 + 2 * k) * HW] * 0.08f;
        float dy = offb[(size_t)(7 + 2 * k) * HW] * 0.08f;
        float pxf = (float)x + dx;
        float pyf = (float)y + dy;
        float x0f = floorf(pxf), y0f = floorf(pyf);
        float wx = pxf - x0f, wy = pyf - y0f;
        int x0 = (int)x0f, y0 = (int)y0f;
        int x1 = x0 + 1, y1 = y0 + 1;
        float vx0 = ((unsigned)x0 < WW) ? 1.f : 0.f;
        float vx1 = ((unsigned)x1 < WW) ? 1.f : 0.f;
        float vy0 = ((unsigned)y0 < HH) ? 1.f : 0.f;
        float vy1 = ((unsigned)y1 < HH) ? 1.f : 0.f;
        int xc0 = min(max(x0, 0), WW - 1), xc1 = min(max(x1, 0), WW - 1);
        int yc0 = min(max(y0, 0), HH - 1), yc1 = min(max(y1, 0), HH - 1);
        float w00 = (1.f - wy) * (1.f - wx) * vy0 * vx0;
        float w01 = (1.f - wy) * wx * vy0 * vx1;
        float w10 = wy * (1.f - wx) * vy1 * vx0;
        float w11 = wy * wx * vy1 * vx1;
        int o00 = yc0 * WW + xc0, o01 = yc0 * WW + xc1;
        int o10 = yc1 * WW + xc0, o11 = yc1 * WW + xc1;

        const float* wk = wgt + (k % 3) * 3 + (k / 3);
#pragma unroll 1
        for (int c = 0; c < 32; ++c) {
            const float* p = inb + (size_t)c * HW;
            float s = w00 * p[o00] + w01 * p[o01] + w10 * p[o10] + w11 * p[o11];
#pragma unroll
            for (int o = 0; o < 32; ++o)
                acc[o] = fmaf(s, wk[(o * 32 + c) * 9], acc[o]);
        }
    }

    const size_t obase = (size_t)b * 32 * HW + pix;
#pragma unroll
    for (int o = 0; o < 32; ++o) {
        float vv = acc[o] + bias[o];
        if (RELU) vv = fmaxf(vv, 0.f);
        if (ADDRES) vv += res[obase + (size_t)o * HW];
        out[obase + (size_t)o * HW] = vv;
    }
}

extern "C" void kernel_launch(void* const* d_in, const int* in_sizes, int n_in,
                              void* d_out, int out_size, void* d_ws, size_t ws_size,
                              hipStream_t stream) {
    const float* x    = (const float*)d_in[0];
    const float* off0 = (const float*)d_in[1];
    const float* w12  = (const float*)d_in[2];
    const float* b12  = (const float*)d_in[3];
    const float* w13a = (const float*)d_in[4];
    const float* b13a = (const float*)d_in[5];
    const float* w13b = (const float*)d_in[6];
    const float* b13b = (const float*)d_in[7];
    const float* w14a = (const float*)d_in[8];
    const float* b14a = (const float*)d_in[9];
    const float* w14b = (const float*)d_in[10];
    const float* b14b = (const float*)d_in[11];
    const float* w15  = (const float*)d_in[12];
    const float* b15  = (const float*)d_in[13];
    const float* w50  = (const float*)d_in[14];
    const float* b50  = (const float*)d_in[15];
    const float* w51  = (const float*)d_in[16];
    const float* b51  = (const float*)d_in[17];
    const float* w60  = (const float*)d_in[18];
    const float* b60  = (const float*)d_in[19];
    const float* w61  = (const float*)d_in[20];
    const float* b61  = (const float*)d_in[21];
    const float* w24  = (const float*)d_in[22];
    const float* b24  = (const float*)d_in[23];

    // ws layout (floats): A (2x64xHW) | B (2x64xHW) | packed bf16 weights
    float* A  = (float*)d_ws;
    float* Bb = A + (size_t)2 * 64 * HW;
    float* D  = Bb;                         // 32-ch aliases of B (B's 64-ch dead)
    float* E  = Bb + (size_t)2 * 32 * HW;
    unsigned short* wpk = (unsigned short*)(Bb + (size_t)2 * 64 * HW);
    const int SZ64 = 64 * 64 * 9;   // 36864 elements
    const int SZ32 = 32 * 64 * 9;   // 18432 elements
    unsigned short* p12  = wpk;
    unsigned short* p13a = p12 + SZ64;
    unsigned short* p13b = p13a + SZ64;
    unsigned short* p14a = p13b + SZ64;
    unsigned short* p14b = p14a + SZ64;
    unsigned short* p15  = p14b + SZ64;
    float* out = (float*)d_out;

    prepack<<<(SZ64 + 255) / 256, 256, 0, stream>>>(w12,  p12,  64, 64);
    prepack<<<(SZ64 + 255) / 256, 256, 0, stream>>>(w13a, p13a, 64, 64);
    prepack<<<(SZ64 + 255) / 256, 256, 0, stream>>>(w13b, p13b, 64, 64);
    prepack<<<(SZ64 + 255) / 256, 256, 0, stream>>>(w14a, p14a, 64, 64);
    prepack<<<(SZ64 + 255) / 256, 256, 0, stream>>>(w14b, p14b, 64, 64);
    prepack<<<(SZ32 + 255) / 256, 256, 0, stream>>>(w15,  p15,  32, 64);

    dim3 gm(WW / 32, HH / 4, 2);  // 8 x 64 x 2

    convmfma<64, 64, false, false><<<gm, 256, 0, stream>>>(x,  p12,  b12,  nullptr, A);
    convmfma<64, 64, true,  false><<<gm, 256, 0, stream>>>(A,  p13a, b13a, nullptr, Bb);
    convmfma<64, 64, false, true ><<<gm, 256, 0, stream>>>(Bb, p13b, b13b, A, A);
    convmfma<64, 64, true,  false><<<gm, 256, 0, stream>>>(A,  p14a, b14a, nullptr, Bb);
    convmfma<64, 64, false, true ><<<gm, 256, 0, stream>>>(Bb, p14b, b14b, A, A);
    convmfma<64, 32, false, false><<<gm, 128, 0, stream>>>(A,  p15,  b15,  nullptr, D);

    dconv32<true,  false><<<512, 256, 0, stream>>>(D, off0, w50, b50, nullptr, E);
    dconv32<false, true ><<<512, 256, 0, stream>>>(E, off0, w51, b51, D, D);
    dconv32<true,  false><<<512, 256, 0, stream>>>(D, off0, w60, b60, nullptr, E);
    dconv32<false, true ><<<512, 256, 0, stream>>>(E, off0, w61, b61, D, D);

    dim3 gs(HH / 16, WW / 16, 2);
    conv3k<32, 3, false, false><<<gs, 256, 0, stream>>>(D, w24, b24, nullptr, out);
}

// Round 3
// 350.004 us; speedup vs baseline: 11.5718x; 2.5210x over previous
//
#include <hip/hip_runtime.h>

#define HH 256
#define WW 256
#define HW (HH * WW)

typedef float f32x4 __attribute__((ext_vector_type(4)));
typedef short bf16x8 __attribute__((ext_vector_type(8)));

__device__ __forceinline__ unsigned short f2bf(float f) {
    union { float f; unsigned u; } v; v.f = f;
    unsigned r = v.u + 0x7fff + ((v.u >> 16) & 1);   // RNE
    return (unsigned short)(r >> 16);
}
__device__ __forceinline__ float bflo(unsigned u) {
    union { unsigned u; float f; } v; v.u = u << 16; return v.f;
}
__device__ __forceinline__ float bfhi(unsigned u) {
    union { unsigned u; float f; } v; v.u = u & 0xffff0000u; return v.f;
}

// ---------------------------------------------------------------------------
// Weight prepack: fp32 OIHW -> bf16 [tap][kc][cout][k32]; tap t uses spatial
// weight w[o][cin][t/3][t%3]. A-frag for lane = contiguous 16B.
// ---------------------------------------------------------------------------
__global__ void prepack(const float* __restrict__ w, unsigned short* __restrict__ dst,
                        int COUT, int CIN) {
    int n = COUT * CIN * 9;
    int i = blockIdx.x * 256 + threadIdx.x;
    if (i >= n) return;
    int q = i & 31;
    int rest = i >> 5;
    int o = rest % COUT;
    int rest2 = rest / COUT;
    int KC = CIN >> 5;
    int kc = rest2 % KC;
    int t = rest2 / KC;
    int cin = kc * 32 + q;
    float v = w[((o * CIN + cin) * 3 + t / 3) * 3 + (t % 3)];
    dst[i] = f2bf(v);
}

// ---------------------------------------------------------------------------
// 3x3 conv via bf16 MFMA implicit GEMM (unchanged from round 2).
// ---------------------------------------------------------------------------
template <int CIN, int COUT, bool RELU, bool ADDRES>
__global__ __launch_bounds__((COUT / 32) * 128) void convmfma(
    const float* __restrict__ in, const unsigned short* __restrict__ wp,
    const float* __restrict__ bias, const float* __restrict__ res,
    float* __restrict__ out) {
    constexpr int KC = CIN / 32;
    constexpr int WM = COUT / 32;
    constexpr int NT = WM * 128;
    constexpr int CSTR = (CIN == 64) ? 72 : 40;
    __shared__ unsigned short xt[204 * CSTR];

    const int tid = threadIdx.x;
    const int b = blockIdx.z;
    const int bx0 = blockIdx.x * 32;
    const int by0 = blockIdx.y * 4;

    const float* inb = in + (size_t)b * CIN * HW;
    for (int hp = tid; hp < 204; hp += NT) {
        int hy = hp / 34, hx = hp - hy * 34;
        int gy = by0 + hy - 1, gx = bx0 + hx - 1;
        bool ok = ((unsigned)gy < HH) && ((unsigned)gx < WW);
        const float* src = inb + ((size_t)gy * WW + gx);
        unsigned* dstp = (unsigned*)&xt[hp * CSTR];
#pragma unroll 4
        for (int c = 0; c < CIN; c += 2) {
            float v0 = ok ? src[(size_t)c * HW] : 0.f;
            float v1 = ok ? src[(size_t)(c + 1) * HW] : 0.f;
            dstp[c >> 1] = (unsigned)f2bf(v0) | ((unsigned)f2bf(v1) << 16);
        }
    }
    __syncthreads();

    const int lane = tid & 63;
    const int wv = tid >> 6;
    const int wm = (WM == 2) ? (wv & 1) : 0;
    const int wn = (WM == 2) ? (wv >> 1) : wv;
    const int l15 = lane & 15;
    const int kg = lane >> 4;

    f32x4 acc[2][4];
#pragma unroll
    for (int m = 0; m < 2; ++m)
#pragma unroll
        for (int n = 0; n < 4; ++n) acc[m][n] = {0.f, 0.f, 0.f, 0.f};

    int hbase[4];
#pragma unroll
    for (int n = 0; n < 4; ++n) {
        int p = wn * 64 + n * 16 + l15;
        hbase[n] = (p >> 5) * 34 + (p & 31);
    }

    const unsigned short* wlane = wp + ((size_t)(wm * 32 + l15) * 4 + kg) * 8;

#pragma unroll
    for (int t = 0; t < 9; ++t) {
        bf16x8 afr[2][KC];
#pragma unroll
        for (int kc = 0; kc < KC; ++kc)
#pragma unroll
            for (int m = 0; m < 2; ++m)
                afr[m][kc] = *(const bf16x8*)(wlane + ((size_t)(t * KC + kc) * COUT + m * 16) * 32);

        const int hoff = (t / 3) * 34 + (t % 3);
#pragma unroll
        for (int kc = 0; kc < KC; ++kc) {
            bf16x8 bfr[4];
#pragma unroll
            for (int n = 0; n < 4; ++n) {
                const unsigned short* pB = &xt[(hbase[n] + hoff) * CSTR + kc * 32 + kg * 8];
                bfr[n] = *(const bf16x8*)pB;
            }
#pragma unroll
            for (int m = 0; m < 2; ++m)
#pragma unroll
                for (int n = 0; n < 4; ++n)
                    acc[m][n] = __builtin_amdgcn_mfma_f32_16x16x32_bf16(afr[m][kc], bfr[n], acc[m][n], 0, 0, 0);
        }
    }

    const size_t obase = (size_t)b * COUT * HW;
#pragma unroll
    for (int m = 0; m < 2; ++m) {
#pragma unroll
        for (int n = 0; n < 4; ++n) {
            int p = wn * 64 + n * 16 + l15;
            int gy = by0 + (p >> 5), gx = bx0 + (p & 31);
#pragma unroll
            for (int r = 0; r < 4; ++r) {
                int cout = wm * 32 + m * 16 + kg * 4 + r;
                float v = acc[m][n][r] + bias[cout];
                if (RELU) v = fmaxf(v, 0.f);
                size_t oi = obase + (size_t)cout * HW + (size_t)gy * WW + gx;
                if (ADDRES) v += res[oi];
                out[oi] = v;
            }
        }
    }
}

// ---------------------------------------------------------------------------
// Deformable 3x3 conv 32->32 via bf16 MFMA. Tile 32x8 px (+2 halo -> 36x12
// staged bf16 pixel-major, stride 40). Lane = pixel, lane-group kg = 8-ch
// k-slice: bilinear lerp computed in registers lands directly in B-frag
// layout. Packed tap t corresponds to deform tap k=(t%3)*3+t/3 (offset chans
// 6+2k / 7+2k). Per-lane global fallback if a corner leaves the staged tile.
// ---------------------------------------------------------------------------
template <bool RELU, bool ADDRES>
__global__ __launch_bounds__(512) void dconvmfma(
    const float* __restrict__ in, const float* __restrict__ off0,
    const unsigned short* __restrict__ wp, const float* __restrict__ bias,
    const float* __restrict__ res, float* __restrict__ out) {
    constexpr int CSTR = 40;
    __shared__ unsigned short xt[432 * CSTR];   // 12 rows x 36 cols

    const int tid = threadIdx.x;
    const int b = blockIdx.z;
    const int bx0 = blockIdx.x * 32;
    const int by0 = blockIdx.y * 8;

    const float* inb = in + (size_t)b * 32 * HW;
    for (int hp = tid; hp < 432; hp += 512) {
        int hy = hp / 36, hx = hp - hy * 36;
        int gy = by0 + hy - 2, gx = bx0 + hx - 2;
        bool ok = ((unsigned)gy < HH) && ((unsigned)gx < WW);
        const float* src = inb + ((size_t)gy * WW + gx);
        unsigned* dstp = (unsigned*)&xt[hp * CSTR];
#pragma unroll 4
        for (int c = 0; c < 32; c += 2) {
            float v0 = ok ? src[(size_t)c * HW] : 0.f;
            float v1 = ok ? src[(size_t)(c + 1) * HW] : 0.f;
            dstp[c >> 1] = (unsigned)f2bf(v0) | ((unsigned)f2bf(v1) << 16);
        }
    }
    __syncthreads();

    const int lane = tid & 63;
    const int wv = tid >> 6;          // 0..7 -> row within tile
    const int l15 = lane & 15;
    const int kg = lane >> 4;

    const int py = by0 + wv;
    const float* offb = off0 + (size_t)b * 24 * HW + (size_t)py * WW;

    f32x4 acc[2][2];
#pragma unroll
    for (int m = 0; m < 2; ++m)
#pragma unroll
        for (int n = 0; n < 2; ++n) acc[m][n] = {0.f, 0.f, 0.f, 0.f};

    const unsigned short* wlane = wp + (size_t)(l15 * 32 + kg * 8);

#pragma unroll 1
    for (int t = 0; t < 9; ++t) {
        const int k = (t % 3) * 3 + t / 3;   // deform tap for packed tap t
        bf16x8 afr[2];
#pragma unroll
        for (int m = 0; m < 2; ++m)
            afr[m] = *(const bf16x8*)(wlane + (size_t)(t * 32 + m * 16) * 32);

        bf16x8 bfr[2];
#pragma unroll
        for (int n = 0; n < 2; ++n) {
            const int pxi = bx0 + n * 16 + l15;
            float dxv = offb[(size_t)(6 + 2 * k) * HW + pxi] * 0.08f;
            float dyv = offb[(size_t)(7 + 2 * k) * HW + pxi] * 0.08f;
            float pxf = (float)pxi + dxv;
            float pyf = (float)py + dyv;
            float x0f = floorf(pxf), y0f = floorf(pyf);
            float wx = pxf - x0f, wy = pyf - y0f;
            int x0 = (int)x0f, y0 = (int)y0f;
            float w00 = (1.f - wy) * (1.f - wx);
            float w01 = (1.f - wy) * wx;
            float w10 = wy * (1.f - wx);
            float w11 = wy * wx;

            union { bf16x8 v; unsigned u[4]; } ures;
            bool intile = (y0 >= by0 - 2) && (y0 <= by0 + 8) &&
                          (x0 >= bx0 - 2) && (x0 <= bx0 + 32);
            if (__builtin_expect(intile, 1)) {
                int lp = (y0 - by0 + 2) * 36 + (x0 - bx0 + 2);
                const unsigned* p00 = (const unsigned*)&xt[lp * CSTR + kg * 8];
                const unsigned* p01 = (const unsigned*)&xt[(lp + 1) * CSTR + kg * 8];
                const unsigned* p10 = (const unsigned*)&xt[(lp + 36) * CSTR + kg * 8];
                const unsigned* p11 = (const unsigned*)&xt[(lp + 37) * CSTR + kg * 8];
                uint4 a00 = *(const uint4*)p00;
                uint4 a01 = *(const uint4*)p01;
                uint4 a10 = *(const uint4*)p10;
                uint4 a11 = *(const uint4*)p11;
                unsigned c00[4] = {a00.x, a00.y, a00.z, a00.w};
                unsigned c01[4] = {a01.x, a01.y, a01.z, a01.w};
                unsigned c10[4] = {a10.x, a10.y, a10.z, a10.w};
                unsigned c11[4] = {a11.x, a11.y, a11.z, a11.w};
#pragma unroll
                for (int j = 0; j < 4; ++j) {
                    float slo = w00 * bflo(c00[j]) + w01 * bflo(c01[j]) +
                                w10 * bflo(c10[j]) + w11 * bflo(c11[j]);
                    float shi = w00 * bfhi(c00[j]) + w01 * bfhi(c01[j]) +
                                w10 * bfhi(c10[j]) + w11 * bfhi(c11[j]);
                    ures.u[j] = (unsigned)f2bf(slo) | ((unsigned)f2bf(shi) << 16);
                }
            } else {
                int x1 = x0 + 1, y1 = y0 + 1;
                float vx0 = ((unsigned)x0 < WW) ? 1.f : 0.f;
                float vx1 = ((unsigned)x1 < WW) ? 1.f : 0.f;
                float vy0 = ((unsigned)y0 < HH) ? 1.f : 0.f;
                float vy1 = ((unsigned)y1 < HH) ? 1.f : 0.f;
                int xc0 = min(max(x0, 0), WW - 1), xc1 = min(max(x1, 0), WW - 1);
                int yc0 = min(max(y0, 0), HH - 1), yc1 = min(max(y1, 0), HH - 1);
                float g00 = w00 * vy0 * vx0, g01 = w01 * vy0 * vx1;
                float g10 = w10 * vy1 * vx0, g11 = w11 * vy1 * vx1;
                int o00 = yc0 * WW + xc0, o01 = yc0 * WW + xc1;
                int o10 = yc1 * WW + xc0, o11 = yc1 * WW + xc1;
#pragma unroll
                for (int j = 0; j < 4; ++j) {
                    unsigned r = 0;
#pragma unroll
                    for (int h = 0; h < 2; ++h) {
                        const float* pc = inb + (size_t)(kg * 8 + j * 2 + h) * HW;
                        float s = g00 * pc[o00] + g01 * pc[o01] +
                                  g10 * pc[o10] + g11 * pc[o11];
                        r |= (unsigned)f2bf(s) << (16 * h);
                    }
                    ures.u[j] = r;
                }
            }
            bfr[n] = ures.v;
        }

#pragma unroll
        for (int m = 0; m < 2; ++m)
#pragma unroll
            for (int n = 0; n < 2; ++n)
                acc[m][n] = __builtin_amdgcn_mfma_f32_16x16x32_bf16(afr[m], bfr[n], acc[m][n], 0, 0, 0);
    }

    const size_t obase = (size_t)b * 32 * HW + (size_t)py * WW;
#pragma unroll
    for (int m = 0; m < 2; ++m) {
#pragma unroll
        for (int n = 0; n < 2; ++n) {
            int gx = bx0 + n * 16 + l15;
#pragma unroll
            for (int r = 0; r < 4; ++r) {
                int cout = m * 16 + kg * 4 + r;
                float v = acc[m][n][r] + bias[cout];
                if (RELU) v = fmaxf(v, 0.f);
                size_t oi = obase + (size_t)cout * HW + gx;
                if (ADDRES) v += res[oi];
                out[oi] = v;
            }
        }
    }
}

// ---------------------------------------------------------------------------
// Direct 3x3 conv (final 32->3 layer).
// ---------------------------------------------------------------------------
template <int CIN, int COUT, bool RELU, bool ADDRES>
__global__ __launch_bounds__(256) void conv3k(const float* __restrict__ in,
                                              const float* __restrict__ wgt,
                                              const float* __restrict__ bias,
                                              const float* __restrict__ res,
                                              float* __restrict__ out) {
    constexpr int CI_CHUNK = 16;
    __shared__ float tile[CI_CHUNK][18][18];

    const int tid = threadIdx.x;
    const int lx = tid & 15, ly = tid >> 4;
    const int bx = blockIdx.x << 4, by = blockIdx.y << 4;
    const int b = blockIdx.z;
    const int px = bx + lx, py = by + ly;

    float acc[COUT];
#pragma unroll
    for (int o = 0; o < COUT; ++o) acc[o] = 0.f;

    const float* inb = in + (size_t)b * CIN * HW;

    for (int c0 = 0; c0 < CIN; c0 += CI_CHUNK) {
        for (int idx = tid; idx < CI_CHUNK * 324; idx += 256) {
            int ci = idx / 324;
            int r = idx - ci * 324;
            int iy = r / 18;
            int ix = r - iy * 18;
            int gy = by - 1 + iy;
            int gx = bx - 1 + ix;
            float v = 0.f;
            if ((unsigned)gy < HH && (unsigned)gx < WW)
                v = inb[(size_t)(c0 + ci) * HW + gy * WW + gx];
            tile[ci][iy][ix] = v;
        }
        __syncthreads();

#pragma unroll 1
        for (int ci = 0; ci < CI_CHUNK; ++ci) {
            float v[9];
#pragma unroll
            for (int t = 0; t < 9; ++t)
                v[t] = tile[ci][ly + t / 3][lx + t % 3];
            const int cg = c0 + ci;
#pragma unroll
            for (int o = 0; o < COUT; ++o) {
                const float* wo = wgt + ((size_t)o * CIN + cg) * 9;
                float a = acc[o];
#pragma unroll
                for (int t = 0; t < 9; ++t) a = fmaf(v[t], wo[t], a);
                acc[o] = a;
            }
        }
        __syncthreads();
    }

    const size_t obase = (size_t)b * COUT * HW + (size_t)py * WW + px;
#pragma unroll
    for (int o = 0; o < COUT; ++o) {
        float vv = acc[o] + bias[o];
        if (RELU) vv = fmaxf(vv, 0.f);
        if (ADDRES) vv += res[obase + (size_t)o * HW];
        out[obase + (size_t)o * HW] = vv;
    }
}

extern "C" void kernel_launch(void* const* d_in, const int* in_sizes, int n_in,
                              void* d_out, int out_size, void* d_ws, size_t ws_size,
                              hipStream_t stream) {
    const float* x    = (const float*)d_in[0];
    const float* off0 = (const float*)d_in[1];
    const float* w12  = (const float*)d_in[2];
    const float* b12  = (const float*)d_in[3];
    const float* w13a = (const float*)d_in[4];
    const float* b13a = (const float*)d_in[5];
    const float* w13b = (const float*)d_in[6];
    const float* b13b = (const float*)d_in[7];
    const float* w14a = (const float*)d_in[8];
    const float* b14a = (const float*)d_in[9];
    const float* w14b = (const float*)d_in[10];
    const float* b14b = (const float*)d_in[11];
    const float* w15  = (const float*)d_in[12];
    const float* b15  = (const float*)d_in[13];
    const float* w50  = (const float*)d_in[14];
    const float* b50  = (const float*)d_in[15];
    const float* w51  = (const float*)d_in[16];
    const float* b51  = (const float*)d_in[17];
    const float* w60  = (const float*)d_in[18];
    const float* b60  = (const float*)d_in[19];
    const float* w61  = (const float*)d_in[20];
    const float* b61  = (const float*)d_in[21];
    const float* w24  = (const float*)d_in[22];
    const float* b24  = (const float*)d_in[23];

    float* A  = (float*)d_ws;
    float* Bb = A + (size_t)2 * 64 * HW;
    float* D  = Bb;
    float* E  = Bb + (size_t)2 * 32 * HW;
    unsigned short* wpk = (unsigned short*)(Bb + (size_t)2 * 64 * HW);
    const int SZ64 = 64 * 64 * 9;
    const int SZ32 = 32 * 64 * 9;
    const int SZD  = 32 * 32 * 9;
    unsigned short* p12  = wpk;
    unsigned short* p13a = p12 + SZ64;
    unsigned short* p13b = p13a + SZ64;
    unsigned short* p14a = p13b + SZ64;
    unsigned short* p14b = p14a + SZ64;
    unsigned short* p15  = p14b + SZ64;
    unsigned short* q50  = p15 + SZ32;
    unsigned short* q51  = q50 + SZD;
    unsigned short* q60  = q51 + SZD;
    unsigned short* q61  = q60 + SZD;
    float* out = (float*)d_out;

    prepack<<<(SZ64 + 255) / 256, 256, 0, stream>>>(w12,  p12,  64, 64);
    prepack<<<(SZ64 + 255) / 256, 256, 0, stream>>>(w13a, p13a, 64, 64);
    prepack<<<(SZ64 + 255) / 256, 256, 0, stream>>>(w13b, p13b, 64, 64);
    prepack<<<(SZ64 + 255) / 256, 256, 0, stream>>>(w14a, p14a, 64, 64);
    prepack<<<(SZ64 + 255) / 256, 256, 0, stream>>>(w14b, p14b, 64, 64);
    prepack<<<(SZ32 + 255) / 256, 256, 0, stream>>>(w15,  p15,  32, 64);
    prepack<<<(SZD  + 255) / 256, 256, 0, stream>>>(w50,  q50,  32, 32);
    prepack<<<(SZD  + 255) / 256, 256, 0, stream>>>(w51,  q51,  32, 32);
    prepack<<<(SZD  + 255) / 256, 256, 0, stream>>>(w60,  q60,  32, 32);
    prepack<<<(SZD  + 255) / 256, 256, 0, stream>>>(w61,  q61,  32, 32);

    dim3 gm(WW / 32, HH / 4, 2);

    convmfma<64, 64, false, false><<<gm, 256, 0, stream>>>(x,  p12,  b12,  nullptr, A);
    convmfma<64, 64, true,  false><<<gm, 256, 0, stream>>>(A,  p13a, b13a, nullptr, Bb);
    convmfma<64, 64, false, true ><<<gm, 256, 0, stream>>>(Bb, p13b, b13b, A, A);
    convmfma<64, 64, true,  false><<<gm, 256, 0, stream>>>(A,  p14a, b14a, nullptr, Bb);
    convmfma<64, 64, false, true ><<<gm, 256, 0, stream>>>(Bb, p14b, b14b, A, A);
    convmfma<64, 32, false, false><<<gm, 128, 0, stream>>>(A,  p15,  b15,  nullptr, D);

    dim3 gd(WW / 32, HH / 8, 2);
    dconvmfma<true,  false><<<gd, 512, 0, stream>>>(D, off0, q50, b50, nullptr, E);
    dconvmfma<false, true ><<<gd, 512, 0, stream>>>(E, off0, q51, b51, D, D);
    dconvmfma<true,  false><<<gd, 512, 0, stream>>>(D, off0, q60, b60, nullptr, E);
    dconvmfma<false, true ><<<gd, 512, 0, stream>>>(E, off0, q61, b61, D, D);

    dim3 gs(HH / 16, WW / 16, 2);
    conv3k<32, 3, false, false><<<gs, 256, 0, stream>>>(D, w24, b24, nullptr, out);
}

// Round 4
// 232.846 us; speedup vs baseline: 17.3942x; 1.5032x over previous
//
#include <hip/hip_runtime.h>

#define HH 256
#define WW 256
#define HW (HH * WW)

typedef float f32x4 __attribute__((ext_vector_type(4)));
typedef short bf16x8 __attribute__((ext_vector_type(8)));

__device__ __forceinline__ unsigned short f2bf(float f) {
    union { float f; unsigned u; } v; v.f = f;
    unsigned r = v.u + 0x7fff + ((v.u >> 16) & 1);   // RNE
    return (unsigned short)(r >> 16);
}
__device__ __forceinline__ float bflo(unsigned u) {
    union { unsigned u; float f; } v; v.u = u << 16; return v.f;
}
__device__ __forceinline__ float bfhi(unsigned u) {
    union { unsigned u; float f; } v; v.u = u & 0xffff0000u; return v.f;
}

// ---------------------------------------------------------------------------
// Merged weight prepack: fp32 OIHW -> bf16 [tap][kc][cout][k32] for all 10
// conv layers in one launch (blockIdx.y = layer). Tap t uses w[o][ci][t/3][t%3].
// ---------------------------------------------------------------------------
__global__ void prepack_all(
    const float* w0, const float* w1, const float* w2, const float* w3,
    const float* w4, const float* w5, const float* w6, const float* w7,
    const float* w8, const float* w9,
    unsigned short* d0, unsigned short* d1, unsigned short* d2,
    unsigned short* d3, unsigned short* d4, unsigned short* d5,
    unsigned short* d6, unsigned short* d7, unsigned short* d8,
    unsigned short* d9) {
    const int L = blockIdx.y;
    const float* w; unsigned short* dst; int COUT, CIN;
    switch (L) {
        case 0: w = w0; dst = d0; COUT = 64; CIN = 64; break;
        case 1: w = w1; dst = d1; COUT = 64; CIN = 64; break;
        case 2: w = w2; dst = d2; COUT = 64; CIN = 64; break;
        case 3: w = w3; dst = d3; COUT = 64; CIN = 64; break;
        case 4: w = w4; dst = d4; COUT = 64; CIN = 64; break;
        case 5: w = w5; dst = d5; COUT = 32; CIN = 64; break;
        case 6: w = w6; dst = d6; COUT = 32; CIN = 32; break;
        case 7: w = w7; dst = d7; COUT = 32; CIN = 32; break;
        case 8: w = w8; dst = d8; COUT = 32; CIN = 32; break;
        default: w = w9; dst = d9; COUT = 32; CIN = 32; break;
    }
    int n = COUT * CIN * 9;
    int i = blockIdx.x * 256 + threadIdx.x;
    if (i >= n) return;
    int q = i & 31;
    int rest = i >> 5;
    int o = rest % COUT;
    int rest2 = rest / COUT;
    int KC = CIN >> 5;
    int kc = rest2 % KC;
    int t = rest2 / KC;
    int cin = kc * 32 + q;
    float v = w[((o * CIN + cin) * 3 + t / 3) * 3 + (t % 3)];
    dst[i] = f2bf(v);
}

// ---------------------------------------------------------------------------
// 3x3 conv via bf16 MFMA implicit GEMM. Activations bf16 NHWC (first layer
// reads fp32 NCHW). Block tile 32x4 px (+1 halo -> 34x6), LDS pixel-major
// stride CSTR. Output bf16 NHWC; fused bias/ReLU/residual.
// ---------------------------------------------------------------------------
template <bool SRCF32, int CIN, int COUT, bool RELU, bool ADDRES>
__global__ __launch_bounds__((COUT / 32) * 128) void convmfma(
    const void* __restrict__ in_, const unsigned short* __restrict__ wp,
    const float* __restrict__ bias, const unsigned short* __restrict__ res,
    unsigned short* __restrict__ out) {
    constexpr int KC = CIN / 32;
    constexpr int WM = COUT / 32;
    constexpr int NT = WM * 128;
    constexpr int CSTR = (CIN == 64) ? 72 : 40;
    __shared__ unsigned short xt[204 * CSTR];

    const int tid = threadIdx.x;
    const int b = blockIdx.z;
    const int bx0 = blockIdx.x * 32;
    const int by0 = blockIdx.y * 4;

    if (SRCF32) {
        const float* inb = (const float*)in_ + (size_t)b * CIN * HW;
        for (int hp = tid; hp < 204; hp += NT) {
            int hy = hp / 34, hx = hp - hy * 34;
            int gy = by0 + hy - 1, gx = bx0 + hx - 1;
            bool ok = ((unsigned)gy < HH) && ((unsigned)gx < WW);
            const float* src = inb + ((size_t)gy * WW + gx);
            unsigned* dstp = (unsigned*)&xt[hp * CSTR];
#pragma unroll 4
            for (int c = 0; c < CIN; c += 2) {
                float v0 = ok ? src[(size_t)c * HW] : 0.f;
                float v1 = ok ? src[(size_t)(c + 1) * HW] : 0.f;
                dstp[c >> 1] = (unsigned)f2bf(v0) | ((unsigned)f2bf(v1) << 16);
            }
        }
    } else {
        const unsigned short* inb = (const unsigned short*)in_ + (size_t)b * HW * CIN;
        constexpr int CH = CIN / 8;   // 16B chunks per pixel
        for (int idx = tid; idx < 204 * CH; idx += NT) {
            int hp = idx / CH, sub = idx - hp * CH;
            int hy = hp / 34, hx = hp - hy * 34;
            int gy = by0 + hy - 1, gx = bx0 + hx - 1;
            uint4 v = {0, 0, 0, 0};
            if (((unsigned)gy < HH) && ((unsigned)gx < WW))
                v = *(const uint4*)&inb[((size_t)gy * WW + gx) * CIN + sub * 8];
            *(uint4*)&xt[hp * CSTR + sub * 8] = v;
        }
    }
    __syncthreads();

    const int lane = tid & 63;
    const int wv = tid >> 6;
    const int wm = (WM == 2) ? (wv & 1) : 0;
    const int wn = (WM == 2) ? (wv >> 1) : wv;
    const int l15 = lane & 15;
    const int kg = lane >> 4;

    f32x4 acc[2][4];
#pragma unroll
    for (int m = 0; m < 2; ++m)
#pragma unroll
        for (int n = 0; n < 4; ++n) acc[m][n] = {0.f, 0.f, 0.f, 0.f};

    int hbase[4];
#pragma unroll
    for (int n = 0; n < 4; ++n) {
        int p = wn * 64 + n * 16 + l15;
        hbase[n] = (p >> 5) * 34 + (p & 31);
    }

    const unsigned short* wlane = wp + ((size_t)(wm * 32 + l15) * 4 + kg) * 8;

#pragma unroll
    for (int t = 0; t < 9; ++t) {
        bf16x8 afr[2][KC];
#pragma unroll
        for (int kc = 0; kc < KC; ++kc)
#pragma unroll
            for (int m = 0; m < 2; ++m)
                afr[m][kc] = *(const bf16x8*)(wlane + ((size_t)(t * KC + kc) * COUT + m * 16) * 32);

        const int hoff = (t / 3) * 34 + (t % 3);
#pragma unroll
        for (int kc = 0; kc < KC; ++kc) {
            bf16x8 bfr[4];
#pragma unroll
            for (int n = 0; n < 4; ++n) {
                const unsigned short* pB = &xt[(hbase[n] + hoff) * CSTR + kc * 32 + kg * 8];
                bfr[n] = *(const bf16x8*)pB;
            }
#pragma unroll
            for (int m = 0; m < 2; ++m)
#pragma unroll
                for (int n = 0; n < 4; ++n)
                    acc[m][n] = __builtin_amdgcn_mfma_f32_16x16x32_bf16(afr[m][kc], bfr[n], acc[m][n], 0, 0, 0);
        }
    }

    // D: col = lane&15 (pixel), row = kg*4+r (cout). Store bf16 NHWC, 8B chunks.
    const size_t pixbase = (size_t)b * HW;
#pragma unroll
    for (int m = 0; m < 2; ++m) {
#pragma unroll
        for (int n = 0; n < 4; ++n) {
            int p = wn * 64 + n * 16 + l15;
            int gy = by0 + (p >> 5), gx = bx0 + (p & 31);
            size_t pidx = (pixbase + (size_t)gy * WW + gx) * COUT;
            int cb = wm * 32 + m * 16 + kg * 4;
            float v[4];
#pragma unroll
            for (int r = 0; r < 4; ++r) {
                v[r] = acc[m][n][r] + bias[cb + r];
                if (RELU) v[r] = fmaxf(v[r], 0.f);
            }
            if (ADDRES) {
                uint2 rr = *(const uint2*)&res[pidx + cb];
                v[0] += bflo(rr.x); v[1] += bfhi(rr.x);
                v[2] += bflo(rr.y); v[3] += bfhi(rr.y);
            }
            uint2 o;
            o.x = (unsigned)f2bf(v[0]) | ((unsigned)f2bf(v[1]) << 16);
            o.y = (unsigned)f2bf(v[2]) | ((unsigned)f2bf(v[3]) << 16);
            *(uint2*)&out[pidx + cb] = o;
        }
    }
}

// ---------------------------------------------------------------------------
// Deformable 3x3 conv 32->32 via bf16 MFMA, activations bf16 NHWC. Tile 32x8
// px (+2 halo -> 36x12, LDS stride 40). Lane = pixel, kg = 8-ch k-slice; the
// bilinear lerp lands directly in B-frag layout. Tap t -> deform tap
// k=(t%3)*3+t/3 (offset chans 6+2k / 7+2k, fp32 NCHW). Global 16B fallback
// per corner when outside the staged tile.
// ---------------------------------------------------------------------------
template <bool RELU, bool ADDRES>
__global__ __launch_bounds__(512) void dconvmfma(
    const unsigned short* __restrict__ in, const float* __restrict__ off0,
    const unsigned short* __restrict__ wp, const float* __restrict__ bias,
    const unsigned short* __restrict__ res, unsigned short* __restrict__ out) {
    constexpr int CSTR = 40;
    __shared__ unsigned short xt[432 * CSTR];

    const int tid = threadIdx.x;
    const int b = blockIdx.z;
    const int bx0 = blockIdx.x * 32;
    const int by0 = blockIdx.y * 8;

    const unsigned short* inb = in + (size_t)b * HW * 32;
    for (int idx = tid; idx < 432 * 4; idx += 512) {
        int hp = idx >> 2, sub = idx & 3;
        int hy = hp / 36, hx = hp - hy * 36;
        int gy = by0 + hy - 2, gx = bx0 + hx - 2;
        uint4 v = {0, 0, 0, 0};
        if (((unsigned)gy < HH) && ((unsigned)gx < WW))
            v = *(const uint4*)&inb[((size_t)gy * WW + gx) * 32 + sub * 8];
        *(uint4*)&xt[hp * CSTR + sub * 8] = v;
    }
    __syncthreads();

    const int lane = tid & 63;
    const int wv = tid >> 6;
    const int l15 = lane & 15;
    const int kg = lane >> 4;

    const int py = by0 + wv;
    const float* offb = off0 + (size_t)b * 24 * HW + (size_t)py * WW;

    f32x4 acc[2][2];
#pragma unroll
    for (int m = 0; m < 2; ++m)
#pragma unroll
        for (int n = 0; n < 2; ++n) acc[m][n] = {0.f, 0.f, 0.f, 0.f};

    const unsigned short* wlane = wp + (size_t)(l15 * 32 + kg * 8);

#pragma unroll 1
    for (int t = 0; t < 9; ++t) {
        const int k = (t % 3) * 3 + t / 3;
        bf16x8 afr[2];
#pragma unroll
        for (int m = 0; m < 2; ++m)
            afr[m] = *(const bf16x8*)(wlane + (size_t)(t * 32 + m * 16) * 32);

        bf16x8 bfr[2];
#pragma unroll
        for (int n = 0; n < 2; ++n) {
            const int pxi = bx0 + n * 16 + l15;
            float dxv = offb[(size_t)(6 + 2 * k) * HW + pxi] * 0.08f;
            float dyv = offb[(size_t)(7 + 2 * k) * HW + pxi] * 0.08f;
            float pxf = (float)pxi + dxv;
            float pyf = (float)py + dyv;
            float x0f = floorf(pxf), y0f = floorf(pyf);
            float wx = pxf - x0f, wy = pyf - y0f;
            int x0 = (int)x0f, y0 = (int)y0f;
            float w00 = (1.f - wy) * (1.f - wx);
            float w01 = (1.f - wy) * wx;
            float w10 = wy * (1.f - wx);
            float w11 = wy * wx;

            uint4 a00, a01, a10, a11;
            float g00, g01, g10, g11;
            bool intile = (y0 >= by0 - 2) && (y0 <= by0 + 8) &&
                          (x0 >= bx0 - 2) && (x0 <= bx0 + 32);
            if (__builtin_expect(intile, 1)) {
                int lp = (y0 - by0 + 2) * 36 + (x0 - bx0 + 2);
                a00 = *(const uint4*)&xt[lp * CSTR + kg * 8];
                a01 = *(const uint4*)&xt[(lp + 1) * CSTR + kg * 8];
                a10 = *(const uint4*)&xt[(lp + 36) * CSTR + kg * 8];
                a11 = *(const uint4*)&xt[(lp + 37) * CSTR + kg * 8];
                g00 = w00; g01 = w01; g10 = w10; g11 = w11;
            } else {
                int x1 = x0 + 1, y1 = y0 + 1;
                float vx0 = ((unsigned)x0 < WW) ? 1.f : 0.f;
                float vx1 = ((unsigned)x1 < WW) ? 1.f : 0.f;
                float vy0 = ((unsigned)y0 < HH) ? 1.f : 0.f;
                float vy1 = ((unsigned)y1 < HH) ? 1.f : 0.f;
                int xc0 = min(max(x0, 0), WW - 1), xc1 = min(max(x1, 0), WW - 1);
                int yc0 = min(max(y0, 0), HH - 1), yc1 = min(max(y1, 0), HH - 1);
                a00 = *(const uint4*)&inb[((size_t)yc0 * WW + xc0) * 32 + kg * 8];
                a01 = *(const uint4*)&inb[((size_t)yc0 * WW + xc1) * 32 + kg * 8];
                a10 = *(const uint4*)&inb[((size_t)yc1 * WW + xc0) * 32 + kg * 8];
                a11 = *(const uint4*)&inb[((size_t)yc1 * WW + xc1) * 32 + kg * 8];
                g00 = w00 * vy0 * vx0; g01 = w01 * vy0 * vx1;
                g10 = w10 * vy1 * vx0; g11 = w11 * vy1 * vx1;
            }
            unsigned c00[4] = {a00.x, a00.y, a00.z, a00.w};
            unsigned c01[4] = {a01.x, a01.y, a01.z, a01.w};
            unsigned c10[4] = {a10.x, a10.y, a10.z, a10.w};
            unsigned c11[4] = {a11.x, a11.y, a11.z, a11.w};
            union { bf16x8 v; unsigned u[4]; } ures;
#pragma unroll
            for (int j = 0; j < 4; ++j) {
                float slo = g00 * bflo(c00[j]) + g01 * bflo(c01[j]) +
                            g10 * bflo(c10[j]) + g11 * bflo(c11[j]);
                float shi = g00 * bfhi(c00[j]) + g01 * bfhi(c01[j]) +
                            g10 * bfhi(c10[j]) + g11 * bfhi(c11[j]);
                ures.u[j] = (unsigned)f2bf(slo) | ((unsigned)f2bf(shi) << 16);
            }
            bfr[n] = ures.v;
        }

#pragma unroll
        for (int m = 0; m < 2; ++m)
#pragma unroll
            for (int n = 0; n < 2; ++n)
                acc[m][n] = __builtin_amdgcn_mfma_f32_16x16x32_bf16(afr[m], bfr[n], acc[m][n], 0, 0, 0);
    }

    const size_t pixbase = (size_t)b * HW + (size_t)py * WW;
#pragma unroll
    for (int m = 0; m < 2; ++m) {
#pragma unroll
        for (int n = 0; n < 2; ++n) {
            int gx = bx0 + n * 16 + l15;
            size_t pidx = (pixbase + gx) * 32;
            int cb = m * 16 + kg * 4;
            float v[4];
#pragma unroll
            for (int r = 0; r < 4; ++r) {
                v[r] = acc[m][n][r] + bias[cb + r];
                if (RELU) v[r] = fmaxf(v[r], 0.f);
            }
            if (ADDRES) {
                uint2 rr = *(const uint2*)&res[pidx + cb];
                v[0] += bflo(rr.x); v[1] += bfhi(rr.x);
                v[2] += bflo(rr.y); v[3] += bfhi(rr.y);
            }
            uint2 o;
            o.x = (unsigned)f2bf(v[0]) | ((unsigned)f2bf(v[1]) << 16);
            o.y = (unsigned)f2bf(v[2]) | ((unsigned)f2bf(v[3]) << 16);
            *(uint2*)&out[pidx + cb] = o;
        }
    }
}

// ---------------------------------------------------------------------------
// Final 3x3 conv 32->3, bf16 NHWC in, fp32 NCHW out. 16x16 tile + halo in
// LDS (stride 34 ushorts, odd bank step), per-thread fp32 FMA.
// ---------------------------------------------------------------------------
__global__ __launch_bounds__(256) void conv3f(const unsigned short* __restrict__ in,
                                              const float* __restrict__ wgt,
                                              const float* __restrict__ bias,
                                              float* __restrict__ out) {
    __shared__ unsigned short xt[324 * 34];
    const int tid = threadIdx.x;
    const int lx = tid & 15, ly = tid >> 4;
    const int bx = blockIdx.x << 4, by = blockIdx.y << 4;
    const int b = blockIdx.z;

    const unsigned short* inb = in + (size_t)b * HW * 32;
    for (int idx = tid; idx < 324 * 8; idx += 256) {
        int hp = idx >> 3, sub = idx & 7;
        int hy = hp / 18, hx = hp - hy * 18;
        int gy = by + hy - 1, gx = bx + hx - 1;
        uint2 v = {0, 0};
        if (((unsigned)gy < HH) && ((unsigned)gx < WW))
            v = *(const uint2*)&inb[((size_t)gy * WW + gx) * 32 + sub * 4];
        *(uint2*)&xt[hp * 34 + sub * 4] = v;
    }
    __syncthreads();

    float a0 = bias[0], a1 = bias[1], a2 = bias[2];
#pragma unroll
    for (int ty = 0; ty < 3; ++ty) {
#pragma unroll
        for (int tx = 0; tx < 3; ++tx) {
            const unsigned short* row = &xt[((ly + ty) * 18 + lx + tx) * 34];
#pragma unroll 8
            for (int c = 0; c < 32; c += 2) {
                unsigned pv = *(const unsigned*)&row[c];
                float vl = bflo(pv), vh = bfhi(pv);
                const float* wl = wgt + (size_t)(c * 3 + ty) * 3 + tx;
                const float* whp = wgt + (size_t)((c + 1) * 3 + ty) * 3 + tx;
                a0 = fmaf(vl, wl[0], a0);          a0 = fmaf(vh, whp[0], a0);
                a1 = fmaf(vl, wl[32 * 9], a1);     a1 = fmaf(vh, whp[32 * 9], a1);
                a2 = fmaf(vl, wl[64 * 9], a2);     a2 = fmaf(vh, whp[64 * 9], a2);
            }
        }
    }
    const size_t o0 = ((size_t)b * 3) * HW + (size_t)(by + ly) * WW + bx + lx;
    out[o0] = a0;
    out[o0 + HW] = a1;
    out[o0 + 2 * HW] = a2;
}

extern "C" void kernel_launch(void* const* d_in, const int* in_sizes, int n_in,
                              void* d_out, int out_size, void* d_ws, size_t ws_size,
                              hipStream_t stream) {
    const float* x    = (const float*)d_in[0];
    const float* off0 = (const float*)d_in[1];
    const float* w12  = (const float*)d_in[2];
    const float* b12  = (const float*)d_in[3];
    const float* w13a = (const float*)d_in[4];
    const float* b13a = (const float*)d_in[5];
    const float* w13b = (const float*)d_in[6];
    const float* b13b = (const float*)d_in[7];
    const float* w14a = (const float*)d_in[8];
    const float* b14a = (const float*)d_in[9];
    const float* w14b = (const float*)d_in[10];
    const float* b14b = (const float*)d_in[11];
    const float* w15  = (const float*)d_in[12];
    const float* b15  = (const float*)d_in[13];
    const float* w50  = (const float*)d_in[14];
    const float* b50  = (const float*)d_in[15];
    const float* w51  = (const float*)d_in[16];
    const float* b51  = (const float*)d_in[17];
    const float* w60  = (const float*)d_in[18];
    const float* b60  = (const float*)d_in[19];
    const float* w61  = (const float*)d_in[20];
    const float* b61  = (const float*)d_in[21];
    const float* w24  = (const float*)d_in[22];
    const float* b24  = (const float*)d_in[23];

    // ws layout (ushort): A (2*HW*64) | B (2*HW*64; D,E alias) | packed weights
    unsigned short* A  = (unsigned short*)d_ws;
    unsigned short* Bb = A + (size_t)2 * HW * 64;
    unsigned short* D  = Bb;
    unsigned short* E  = Bb + (size_t)2 * HW * 32;
    unsigned short* wpk = Bb + (size_t)2 * HW * 64;
    const int SZ64 = 64 * 64 * 9;
    const int SZ32 = 32 * 64 * 9;
    const int SZD  = 32 * 32 * 9;
    unsigned short* p12  = wpk;
    unsigned short* p13a = p12 + SZ64;
    unsigned short* p13b = p13a + SZ64;
    unsigned short* p14a = p13b + SZ64;
    unsigned short* p14b = p14a + SZ64;
    unsigned short* p15  = p14b + SZ64;
    unsigned short* q50  = p15 + SZ32;
    unsigned short* q51  = q50 + SZD;
    unsigned short* q60  = q51 + SZD;
    unsigned short* q61  = q60 + SZD;
    float* out = (float*)d_out;

    prepack_all<<<dim3(144, 10), 256, 0, stream>>>(
        w12, w13a, w13b, w14a, w14b, w15, w50, w51, w60, w61,
        p12, p13a, p13b, p14a, p14b, p15, q50, q51, q60, q61);

    dim3 gm(WW / 32, HH / 4, 2);

    convmfma<true,  64, 64, false, false><<<gm, 256, 0, stream>>>(x,  p12,  b12,  nullptr, A);
    convmfma<false, 64, 64, true,  false><<<gm, 256, 0, stream>>>(A,  p13a, b13a, nullptr, Bb);
    convmfma<false, 64, 64, false, true ><<<gm, 256, 0, stream>>>(Bb, p13b, b13b, A, A);
    convmfma<false, 64, 64, true,  false><<<gm, 256, 0, stream>>>(A,  p14a, b14a, nullptr, Bb);
    convmfma<false, 64, 64, false, true ><<<gm, 256, 0, stream>>>(Bb, p14b, b14b, A, A);
    convmfma<false, 64, 32, false, false><<<gm, 128, 0, stream>>>(A,  p15,  b15,  nullptr, D);

    dim3 gd(WW / 32, HH / 8, 2);
    dconvmfma<true,  false><<<gd, 512, 0, stream>>>(D, off0, q50, b50, nullptr, E);
    dconvmfma<false, true ><<<gd, 512, 0, stream>>>(E, off0, q51, b51, D, D);
    dconvmfma<true,  false><<<gd, 512, 0, stream>>>(D, off0, q60, b60, nullptr, E);
    dconvmfma<false, true ><<<gd, 512, 0, stream>>>(E, off0, q61, b61, D, D);

    dim3 gs(HH / 16, WW / 16, 2);
    conv3f<<<gs, 256, 0, stream>>>(D, w24, b24, out);
}